// Round 1
// baseline (58457.233 us; speedup 1.0000x reference)
//
#include <hip/hip_runtime.h>
#include <math.h>

// ---- problem constants ----
constexpr int SEQ_T   = 2048;
constexpr int BATCH   = 128;
constexpr int KDIM    = 128;
constexpr int VDIM    = 128;
constexpr int EDIM    = 400;
constexpr int HDIM    = 300;
constexpr int GDIM    = 1200;   // 4*H
constexpr int NVOCAB  = 33;
constexpr int XCAT    = 828;    // E+V (528) + H (300)
constexpr int XS_STRIDE = 836;  // padded LDS stride (breaks bank aliasing)
constexpr int MAXLEN  = 500;
constexpr int SOS_TOK = 5;
constexpr long long NLOGITS = (long long)MAXLEN * BATCH * NVOCAB; // 2,112,000

// ---- ws layout (floats) ----
// h:38400 c:38400 gates:153600 query:16384 energy:262144 ctx:16384 wphiT:38400 chars:128(int)
constexpr size_t OFF_H      = 0;
constexpr size_t OFF_C      = 38400;
constexpr size_t OFF_GATES  = 76800;
constexpr size_t OFF_QUERY  = 230400;
constexpr size_t OFF_ENERGY = 246784;
constexpr size_t OFF_CTX    = 508928;
constexpr size_t OFF_WPHIT  = 525312;
constexpr size_t OFF_CHARS  = 563712;

// ---------------------------------------------------------------------------
// one-time: W_phi [128][300] -> W_phiT [300][128] for coalesced query GEMV
__global__ __launch_bounds__(256) void k_transpose(
    const float* __restrict__ W_phi, float* __restrict__ wphiT) {
  int i = blockIdx.x * 256 + threadIdx.x;        // i = j*128 + kq
  if (i < HDIM * KDIM) {
    int j  = i >> 7;          // / 128
    int kq = i & 127;
    wphiT[i] = W_phi[kq * HDIM + j];
  }
}

// one-time: h,c,char init + initial query = b_phi + h0 @ W_phi.T
__global__ __launch_bounds__(128) void k_init(
    const float* __restrict__ h0, const float* __restrict__ c0,
    const float* __restrict__ b_phi, const float* __restrict__ wphiT,
    float* __restrict__ h, float* __restrict__ c,
    float* __restrict__ query, int* __restrict__ chars) {
  const int b = blockIdx.x;
  const int tid = threadIdx.x;
  for (int j = tid; j < HDIM; j += 128) {
    h[b * HDIM + j] = h0[j];
    c[b * HDIM + j] = c0[j];
  }
  {
    float q = b_phi[tid];
    for (int j = 0; j < HDIM; ++j) q += h0[j] * wphiT[j * KDIM + tid];
    query[b * KDIM + tid] = q;
  }
  if (tid == 0) chars[b] = SOS_TOK;
}

// ---------------------------------------------------------------------------
// energy[b][t] = query[b,:] . keys[t,b,:]   (streams keys, 134 MB)
__global__ __launch_bounds__(256) void k_energy(
    const float* __restrict__ keys, const float* __restrict__ query,
    float* __restrict__ energy) {
  const int b     = blockIdx.x;
  const int tbase = blockIdx.y * 128;
  const int tid   = threadIdx.x;
  const int wave  = tid >> 6;       // 0..3
  const int lane  = tid & 63;
  const int half  = lane >> 5;      // which of 2 t's this lane serves
  const int l32   = lane & 31;      // k-quad index
  const float4 q4 = *(const float4*)(query + b * KDIM + l32 * 4);
  const int t0 = tbase + wave * 32;
  for (int i = 0; i < 16; ++i) {
    const int t = t0 + 2 * i + half;
    const float4 kv = *(const float4*)(keys + ((size_t)t * BATCH + b) * KDIM + l32 * 4);
    float p = q4.x * kv.x + q4.y * kv.y + q4.z * kv.z + q4.w * kv.w;
    p += __shfl_xor(p, 1);
    p += __shfl_xor(p, 2);
    p += __shfl_xor(p, 4);
    p += __shfl_xor(p, 8);
    p += __shfl_xor(p, 16);
    if (l32 == 0) energy[b * SEQ_T + t] = p;
  }
}

// softmax over T per b, in place: energy -> attention
__global__ __launch_bounds__(256) void k_stats(float* __restrict__ energy) {
  const int b = blockIdx.x;
  __shared__ float es[SEQ_T];
  __shared__ float red[8];
  const int tid = threadIdx.x;
  float m = -INFINITY;
  for (int t = tid; t < SEQ_T; t += 256) {
    float e = energy[b * SEQ_T + t];
    es[t] = e;
    m = fmaxf(m, e);
  }
  for (int off = 32; off; off >>= 1) m = fmaxf(m, __shfl_xor(m, off));
  if ((tid & 63) == 0) red[tid >> 6] = m;
  __syncthreads();
  const float mb = fmaxf(fmaxf(red[0], red[1]), fmaxf(red[2], red[3]));
  float s = 0.f;
  for (int t = tid; t < SEQ_T; t += 256) {
    float ex = expf(es[t] - mb);
    es[t] = ex;
    s += ex;
  }
  for (int off = 32; off; off >>= 1) s += __shfl_xor(s, off);
  if ((tid & 63) == 0) red[4 + (tid >> 6)] = s;
  __syncthreads();
  const float inv = 1.0f / (red[4] + red[5] + red[6] + red[7]);
  for (int t = tid; t < SEQ_T; t += 256) energy[b * SEQ_T + t] = es[t] * inv;
}

// ctx[b][v] = sum_t att[b][t] * values[t][b][v]   (streams values, 134 MB)
// grid (2 vhalf, 128 b), 512 thr: v4 = tid&15 (64 v per block), tsub = tid>>4
__global__ __launch_bounds__(512) void k_context(
    const float* __restrict__ values, const float* __restrict__ att,
    float* __restrict__ ctx) {
  const int vhalf = blockIdx.x;
  const int b     = blockIdx.y;
  const int tid   = threadIdx.x;
  const int v4    = tid & 15;
  const int tsub  = tid >> 4;    // 0..31
  float4 acc = make_float4(0.f, 0.f, 0.f, 0.f);
  for (int i = 0; i < 64; ++i) {
    const int t = i * 32 + tsub;
    const float a = att[b * SEQ_T + t];
    const float4 val = *(const float4*)(values + ((size_t)t * BATCH + b) * VDIM
                                        + vhalf * 64 + v4 * 4);
    acc.x += a * val.x; acc.y += a * val.y; acc.z += a * val.z; acc.w += a * val.w;
  }
  __shared__ float4 red[32][16];
  red[tsub][v4] = acc;
  __syncthreads();
  if (tid < 16) {
    float4 s = red[0][tid];
    for (int p = 1; p < 32; ++p) {          // fixed order -> deterministic
      float4 r = red[p][tid];
      s.x += r.x; s.y += r.y; s.z += r.z; s.w += r.w;
    }
    *(float4*)(ctx + b * VDIM + vhalf * 64 + tid * 4) = s;
  }
}

// ---------------------------------------------------------------------------
// gates[b][j] = x @ W_ih.T + b_ih + h @ W_hh.T + b_hh,  x = [emb[char], ctx]
// tile: 16 b x 32 j per block; x staged in LDS; each thread 2 j outputs
__global__ __launch_bounds__(256) void k_gates(
    const float* __restrict__ emb, const int* __restrict__ chars,
    const float* __restrict__ ctx, const float* __restrict__ h,
    const float* __restrict__ W_ih, const float* __restrict__ b_ih,
    const float* __restrict__ W_hh, const float* __restrict__ b_hh,
    float* __restrict__ gates) {
  const int bT = blockIdx.x * 16;
  const int jT = blockIdx.y * 32;
  const int tid = threadIdx.x;
  __shared__ float Xs[16 * XS_STRIDE];
  // stage x = [emb(400) | ctx(128) | h(300) | 0-pad]
  for (int bb = 0; bb < 16; ++bb) {
    const int bg = bT + bb;
    const int ch = chars[bg];
    for (int k = tid; k < 832; k += 256) {
      float x;
      if (k < EDIM)            x = emb[ch * EDIM + k];
      else if (k < EDIM + VDIM) x = ctx[bg * VDIM + (k - EDIM)];
      else if (k < XCAT)        x = h[bg * HDIM + (k - (EDIM + VDIM))];
      else                      x = 0.f;
      Xs[bb * XS_STRIDE + k] = x;
    }
  }
  __syncthreads();
  const int bLoc = tid & 15;
  const int jLoc = tid >> 4;            // 0..15
  const int j0 = jT + jLoc * 2;
  if (j0 >= GDIM) return;
  const int j1 = j0 + 1;
  const int bg = bT + bLoc;
  float acc0 = 0.f, acc1 = 0.f;
  const float4* xr = (const float4*)(Xs + bLoc * XS_STRIDE);
  {
    const float4* w0 = (const float4*)(W_ih + (size_t)j0 * 528);
    const float4* w1 = (const float4*)(W_ih + (size_t)j1 * 528);
    for (int k4 = 0; k4 < 132; ++k4) {   // k 0..527
      const float4 xv = xr[k4];
      const float4 a = w0[k4];
      const float4 bv = w1[k4];
      acc0 += xv.x * a.x + xv.y * a.y + xv.z * a.z + xv.w * a.w;
      acc1 += xv.x * bv.x + xv.y * bv.y + xv.z * bv.z + xv.w * bv.w;
    }
  }
  {
    const float4* xh = (const float4*)(Xs + bLoc * XS_STRIDE + 528);
    const float4* g0 = (const float4*)(W_hh + (size_t)j0 * HDIM);
    const float4* g1 = (const float4*)(W_hh + (size_t)j1 * HDIM);
    for (int k4 = 0; k4 < 75; ++k4) {    // k 528..827 -> h 0..299
      const float4 xv = xh[k4];
      const float4 a = g0[k4];
      const float4 bv = g1[k4];
      acc0 += xv.x * a.x + xv.y * a.y + xv.z * a.z + xv.w * a.w;
      acc1 += xv.x * bv.x + xv.y * bv.y + xv.z * bv.z + xv.w * bv.w;
    }
  }
  gates[bg * GDIM + j0] = acc0 + b_ih[j0] + b_hh[j0];
  gates[bg * GDIM + j1] = acc1 + b_ih[j1] + b_hh[j1];
}

// LSTM cell + logits + argmax + query; one block per b, 320 threads (5 waves)
__global__ __launch_bounds__(320) void k_fused2(
    const float* __restrict__ gates, const float* __restrict__ ctx,
    const float* __restrict__ W_proj, const float* __restrict__ b_proj,
    const float* __restrict__ b_phi, const float* __restrict__ wphiT,
    float* __restrict__ h, float* __restrict__ c,
    float* __restrict__ query, int* __restrict__ chars,
    float* __restrict__ out, int step) {
  const int b = blockIdx.x;
  const int tid = threadIdx.x;
  __shared__ float cat_s[HDIM + VDIM];   // [h(300) | ctx(128)]
  __shared__ float logit_s[NVOCAB];
  // stage 1: cell
  if (tid < HDIM) {
    const float gi = gates[b * GDIM + tid];
    const float gf = gates[b * GDIM + HDIM + tid];
    const float gg = gates[b * GDIM + 2 * HDIM + tid];
    const float go = gates[b * GDIM + 3 * HDIM + tid];
    const float cc = c[b * HDIM + tid];
    const float si = 1.f / (1.f + expf(-gi));
    const float sf = 1.f / (1.f + expf(-gf));
    const float so = 1.f / (1.f + expf(-go));
    const float cn = sf * cc + si * tanhf(gg);
    const float hn = so * tanhf(cn);
    c[b * HDIM + tid] = cn;
    h[b * HDIM + tid] = hn;
    cat_s[tid] = hn;
  }
  if (tid < VDIM) cat_s[HDIM + tid] = ctx[b * VDIM + tid];
  __syncthreads();
  // stage 2: logits = cat . W_proj[j,:] + b_proj[j], wave per logit
  {
    const int w = tid >> 6, l = tid & 63;
    for (int j = w; j < NVOCAB; j += 5) {
      float p = 0.f;
      for (int e = l; e < HDIM + VDIM; e += 64) p += cat_s[e] * W_proj[j * 428 + e];
      p += __shfl_xor(p, 1);
      p += __shfl_xor(p, 2);
      p += __shfl_xor(p, 4);
      p += __shfl_xor(p, 8);
      p += __shfl_xor(p, 16);
      p += __shfl_xor(p, 32);
      if (l == 0) logit_s[j] = p + b_proj[j];
    }
  }
  __syncthreads();
  // stage 3: emit logits + argmax (first-max tie-break, matches np.argmax)
  if (tid < NVOCAB) out[((size_t)step * BATCH + b) * NVOCAB + tid] = logit_s[tid];
  if (tid == 0) {
    float best = logit_s[0];
    int bi = 0;
    for (int j = 1; j < NVOCAB; ++j)
      if (logit_s[j] > best) { best = logit_s[j]; bi = j; }
    chars[b] = bi;
    out[NLOGITS + (size_t)step * BATCH + b] = (float)bi;
  }
  // stage 4: query[b][k] = b_phi[k] + h_new . W_phi[k,:]  (via W_phiT, coalesced)
  if (tid < KDIM) {
    float q = b_phi[tid];
    for (int j = 0; j < HDIM; ++j) q += cat_s[j] * wphiT[j * KDIM + tid];
    query[b * KDIM + tid] = q;
  }
}

// ---------------------------------------------------------------------------
extern "C" void kernel_launch(void* const* d_in, const int* in_sizes, int n_in,
                              void* d_out, int out_size, void* d_ws, size_t ws_size,
                              hipStream_t stream) {
  const float* keys   = (const float*)d_in[0];
  const float* values = (const float*)d_in[1];
  const float* emb    = (const float*)d_in[2];
  const float* W_phi  = (const float*)d_in[3];
  const float* b_phi  = (const float*)d_in[4];
  const float* W_ih   = (const float*)d_in[5];
  const float* b_ih   = (const float*)d_in[6];
  const float* W_hh   = (const float*)d_in[7];
  const float* b_hh   = (const float*)d_in[8];
  const float* W_proj = (const float*)d_in[9];
  const float* b_proj = (const float*)d_in[10];
  const float* h0     = (const float*)d_in[11];
  const float* c0     = (const float*)d_in[12];
  float* out = (float*)d_out;

  float* W = (float*)d_ws;
  float* f_h      = W + OFF_H;
  float* f_c      = W + OFF_C;
  float* f_gates  = W + OFF_GATES;
  float* f_query  = W + OFF_QUERY;
  float* f_energy = W + OFF_ENERGY;   // reused as attention after k_stats
  float* f_ctx    = W + OFF_CTX;
  float* f_wphiT  = W + OFF_WPHIT;
  int*   i_chars  = (int*)(W + OFF_CHARS);

  // one-time preprocessing + initial attend(h0)
  k_transpose<<<150, 256, 0, stream>>>(W_phi, f_wphiT);
  k_init<<<BATCH, 128, 0, stream>>>(h0, c0, b_phi, f_wphiT, f_h, f_c, f_query, i_chars);
  k_energy<<<dim3(BATCH, 16), 256, 0, stream>>>(keys, f_query, f_energy);
  k_stats<<<BATCH, 256, 0, stream>>>(f_energy);
  k_context<<<dim3(2, BATCH), 512, 0, stream>>>(values, f_energy, f_ctx);

  for (int s = 0; s < MAXLEN; ++s) {
    k_gates<<<dim3(8, 38), 256, 0, stream>>>(emb, i_chars, f_ctx, f_h,
                                             W_ih, b_ih, W_hh, b_hh, f_gates);
    k_fused2<<<BATCH, 320, 0, stream>>>(f_gates, f_ctx, W_proj, b_proj,
                                        b_phi, f_wphiT, f_h, f_c,
                                        f_query, i_chars, out, s);
    k_energy<<<dim3(BATCH, 16), 256, 0, stream>>>(keys, f_query, f_energy);
    k_stats<<<BATCH, 256, 0, stream>>>(f_energy);
    k_context<<<dim3(2, BATCH), 512, 0, stream>>>(values, f_energy, f_ctx);
  }
}